// Round 17
// baseline (113.057 us; speedup 1.0000x reference)
//
#include <hip/hip_runtime.h>
#include <hip/hip_bf16.h>
#include <math.h>

#define DEVI static __device__ __forceinline__

using f32x4  = __attribute__((ext_vector_type(4))) float;
using f32x16 = __attribute__((ext_vector_type(16))) float;
using s16x8  = __attribute__((ext_vector_type(8))) short;
using bf16x8 = __attribute__((ext_vector_type(8))) __bf16;
using i32x4  = __attribute__((ext_vector_type(4))) int;
using u32x2  = __attribute__((ext_vector_type(2))) unsigned int;
using u32x4  = __attribute__((ext_vector_type(4))) unsigned int;

constexpr int N   = 8192;
constexpr int KIN = 512;
constexpr int F   = 256;

DEVI unsigned f2bf(float f) {
  unsigned u = __builtin_bit_cast(unsigned, f);
  return ((u + 0x7FFFu + ((u >> 16) & 1u)) >> 16) & 0xFFFFu;
}

DEVI float bfLO(unsigned u) { return __builtin_bit_cast(float, (u & 0xFFFFu) << 16); }
DEVI float bfHI(unsigned u) { return __builtin_bit_cast(float, u & 0xFFFF0000u); }

DEVI unsigned cvtpk(float lo, float hi) {
  unsigned r;
  asm("v_cvt_pk_bf16_f32 %0, %1, %2" : "=v"(r) : "v"(lo), "v"(hi));
  return r;
}

DEVI f32x16 mfma32(s16x8 a, s16x8 b, f32x16 c) {
  return __builtin_amdgcn_mfma_f32_32x32x16_bf16(
      __builtin_bit_cast(bf16x8, a), __builtin_bit_cast(bf16x8, b), c, 0, 0, 0);
}

DEVI void gload16(const void* g, void* lds_uniform) {
  __builtin_amdgcn_global_load_lds(
      (const __attribute__((address_space(1))) unsigned*)g,
      (__attribute__((address_space(3))) unsigned*)lds_uniform, 16, 0, 0);
}

// ---------------- W [512][256] f32 -> Wt [256][512] bf16 (transposed) -----------
__global__ __launch_bounds__(256) void k_prep_w(const float* __restrict__ W,
                                                unsigned short* __restrict__ Wt) {
  int t = blockIdx.x * 256 + threadIdx.x;   // 16384 threads
  int c = t >> 6, k0 = (t & 63) * 8;
  s16x8 o;
#pragma unroll
  for (int i = 0; i < 8; ++i) o[i] = (short)f2bf(W[(size_t)(k0 + i) * F + c]);
  *(s16x8*)(Wt + (size_t)c * KIN + k0) = o;
}

// ---------------- h = X @ Wt^T (cast fused) : Hj + E/E5/FG ----------------------
// Hj layout [512 j-groups][256 feats][16 j] bf16 (R7-verified) so phase2 B-frags
// are 2KB-contiguous coalesced global loads. A staged raw-f32 via gload_lds with
// pre-swizzled source; in-register v_cvt_pk_bf16_f32 (RNE, matches f2bf).
__global__ __launch_bounds__(512) void k_gemm1(const float* __restrict__ input,
                                               const unsigned short* __restrict__ Wt,
                                               const float* __restrict__ a_vec,
                                               unsigned short* __restrict__ Hj,
                                               float* __restrict__ E, float* __restrict__ E5,
                                               unsigned* __restrict__ FG) {
  __shared__ __align__(16) char lds[8192 + 32768 + 2048];
  char* ldsA = lds;                 // [32 rows][256 B] f32 (16B-unit XOR-swizzled)
  char* ldsW = lds + 8192;          // [256 cols][128 B] bf16 (XOR-swizzled)
  float* red = (float*)(lds + 8192 + 32768); // [2][32][8]
  int tid = threadIdx.x, w = tid >> 6, l = tid & 63;
  int r0 = blockIdx.x * 32;
  f32x16 acc;
#pragma unroll
  for (int i = 0; i < 16; ++i) acc[i] = 0.f;

  int lrow8 = l >> 3;
  int koffB = ((l & 7) ^ lrow8) * 8;   // pre-swizzled source k-offset (bf16 elems)
  int ra = l & 31, kb = (l >> 5) * 8;
  int colw = w * 32 + ra;

  // A staging role: thread covers row arow, 16B chunk ac16 (4 f32)
  const int arow = tid >> 4, ac16 = tid & 15;
  const int aoff = (ac16 * 4) ^ ((arow & 7) << 2);   // pre-swizzled f32 elem off
  const float* aR = input + (size_t)(r0 + arow) * KIN + aoff;

  for (int it = 0; it < 8; ++it) {
    int k0 = it * 64;
    __syncthreads();
    gload16(aR + k0, ldsA + w * 1024);
#pragma unroll
    for (int qi = 0; qi < 4; ++qi) {
      int q = 4 * w + qi;
      int c = 8 * q + lrow8;
      gload16(Wt + (size_t)c * KIN + k0 + koffB, ldsW + q * 1024);
    }
    __syncthreads();
    s16x8 av[4], bv[4];
#pragma unroll
    for (int kf = 0; kf < 4; ++kf) {
      int e4 = (kf * 16 + kb) * 4;
      f32x4 a0 = *(const f32x4*)(ldsA + ra * 256 + (e4 ^ ((ra & 7) << 4)));
      f32x4 a1 = *(const f32x4*)(ldsA + ra * 256 + ((e4 + 16) ^ ((ra & 7) << 4)));
      u32x4 ap;
      ap[0] = cvtpk(a0[0], a0[1]); ap[1] = cvtpk(a0[2], a0[3]);
      ap[2] = cvtpk(a1[0], a1[1]); ap[3] = cvtpk(a1[2], a1[3]);
      av[kf] = __builtin_bit_cast(s16x8, ap);
      int kk2 = (kf * 16 + kb) * 2;
      bv[kf] = *(const s16x8*)(ldsW + colw * 128 + (kk2 ^ ((colw & 7) << 4)));
    }
#pragma unroll
    for (int kf = 0; kf < 4; ++kf) acc = mfma32(av[kf], bv[kf], acc);
  }

  float a1v = a_vec[colw], a2v = a_vec[256 + colw];
  int rquad = (l >> 5) * 4;
#pragma unroll
  for (int g = 0; g < 4; ++g) {
    int jj = r0 + g * 8 + rquad;        // 4-aligned; same 16-group for jj..jj+3
    unsigned h0 = f2bf(acc[g * 4 + 0]), h1 = f2bf(acc[g * 4 + 1]);
    unsigned h2 = f2bf(acc[g * 4 + 2]), h3 = f2bf(acc[g * 4 + 3]);
    u32x2 pk;
    pk[0] = h0 | (h1 << 16);
    pk[1] = h2 | (h3 << 16);
    *(u32x2*)(Hj + ((size_t)(jj >> 4)) * 4096 + colw * 16 + (jj & 15)) = pk;
  }
#pragma unroll
  for (int g = 0; g < 16; ++g) {
    float vs = acc[g] * a1v;
    float vn = acc[g] * a2v;
#pragma unroll
    for (int m = 1; m <= 16; m <<= 1) {
      vs += __shfl_xor(vs, m, 64);
      vn += __shfl_xor(vn, m, 64);
    }
    if ((l & 31) == 0) {
      int row = (g & 3) + 8 * (g >> 2) + rquad;
      red[row * 8 + w] = vs;
      red[256 + row * 8 + w] = vn;
    }
  }
  __syncthreads();
  if (tid < 32) {
    float s = 0.f, n2 = 0.f;
#pragma unroll
    for (int i = 0; i < 8; ++i) { s += red[tid * 8 + i]; n2 += red[256 + tid * 8 + i]; }
    E[r0 + tid]  = expf(s);
    E5[r0 + tid] = expf(0.2f * s);
    FG[r0 + tid] = f2bf(expf(n2)) | (f2bf(expf(0.2f * n2)) << 16);
  }
}

// ---------------- fused masked-softmax-numerator @ h: B-direct-from-L2 ----------
// grid 512 = 128 row-blocks (64 rows) x KSPLIT=4; 512 threads, 8 waves,
// 2 blocks/CU. LDS = ONLY the 8KB P buffer (H staging eliminated): B fragments
// load straight from L2-resident Hj (2KB contiguous per fragment), issued at
// iter top so P-gen + barrier (~500cy) covers L2 latency. Wave role: rg = w&1
// (row half) x cp = w>>1 (64-feat col-pair), ALL k per wave -> acc 2 x f32x16
// (32 AGPR), no epilogue merge. P handoff keeps R12's proven single-buffer
// 2-barrier discipline; no vmcnt asm needed (no gload_lds in flight).
__global__ __launch_bounds__(512, 4) void k_phase2(const int* __restrict__ adj,
                                                   const unsigned short* __restrict__ Hj,
                                                   const float* __restrict__ E,
                                                   const float* __restrict__ E5,
                                                   const unsigned* __restrict__ FG,
                                                   unsigned short* __restrict__ pacc,
                                                   float* __restrict__ ps) {
  __shared__ __align__(16) char ldsP[8192];   // [64 rows][64 j] bf16, swizzled

  const int tid = threadIdx.x, w = tid >> 6, l = tid & 63;
  const int rb = blockIdx.x >> 2, ks = blockIdx.x & 3;
  const int r0 = rb * 64;
  const int jb = ks * 2048;

  // producer role (all threads): row r, j-chunk jc8 (8 j)
  const int r = tid >> 3, jc8 = (tid & 7) * 8;
  const float Er = E[r0 + r], E5r = E5[r0 + r];
  float s_part = 0.f;
  const int*      __restrict__ adjR = adj + (size_t)(r0 + r) * N + jb + jc8;
  const unsigned* __restrict__ fgR  = FG + jb + jc8;
  const int pw_byte = r * 128 + ((jc8 * 2) ^ ((r & 7) << 4));

  // consumer role: rg = row half, cp = 64-feat col pair; all 4 k-steps
  const int rg = w & 1, cp = w >> 1;
  const int ra = rg * 32 + (l & 31);
  const int khb = (l >> 5) * 16;
  const int colb = cp * 64 + (l & 31);
  const int swzA = (ra & 7) << 4;
  const int kh8 = (l >> 5) * 8;
  // B fragment base: elem ((jb>>4)+it*4+kt)*4096 + col*16 + kh8 (2KB coalesced)
  const unsigned short* __restrict__ HjB =
      Hj + (size_t)(jb >> 4) * 4096 + colb * 16 + kh8;

  f32x16 acc0, acc1;
#pragma unroll
  for (int i = 0; i < 16; ++i) { acc0[i] = 0.f; acc1[i] = 0.f; }

  // ---- prologue: pf(0) ----
  i32x4 ad0 = *(const i32x4*)(adjR);
  i32x4 ad1 = *(const i32x4*)(adjR + 4);
  u32x4 fc0 = *(const u32x4*)(fgR);
  u32x4 fc1 = *(const u32x4*)(fgR + 4);

  for (int it = 0; it < 32; ++it) {
    const int jn = ((it + 1) & 31) * 64;
    const unsigned short* hb = HjB + (size_t)it * 16384;

    // 1. issue B loads for this iter (8 x 16B/lane, L2-resident, coalesced)
    s16x8 b00 = *(const s16x8*)(hb);
    s16x8 b01 = *(const s16x8*)(hb + 512);
    s16x8 b10 = *(const s16x8*)(hb + 4096);
    s16x8 b11 = *(const s16x8*)(hb + 4096 + 512);
    s16x8 b20 = *(const s16x8*)(hb + 8192);
    s16x8 b21 = *(const s16x8*)(hb + 8192 + 512);
    s16x8 b30 = *(const s16x8*)(hb + 12288);
    s16x8 b31 = *(const s16x8*)(hb + 12288 + 512);

    // 2. P-gen(it): p = adj ? max(Er*F, E5r*G) : 0 (exact LeakyReLU-exp identity)
    {
      float p0 = (ad0[0] != 0) ? fmaxf(Er * bfLO(fc0[0]), E5r * bfHI(fc0[0])) : 0.f;
      float p1 = (ad0[1] != 0) ? fmaxf(Er * bfLO(fc0[1]), E5r * bfHI(fc0[1])) : 0.f;
      float p2 = (ad0[2] != 0) ? fmaxf(Er * bfLO(fc0[2]), E5r * bfHI(fc0[2])) : 0.f;
      float p3 = (ad0[3] != 0) ? fmaxf(Er * bfLO(fc0[3]), E5r * bfHI(fc0[3])) : 0.f;
      float p4 = (ad1[0] != 0) ? fmaxf(Er * bfLO(fc1[0]), E5r * bfHI(fc1[0])) : 0.f;
      float p5 = (ad1[1] != 0) ? fmaxf(Er * bfLO(fc1[1]), E5r * bfHI(fc1[1])) : 0.f;
      float p6 = (ad1[2] != 0) ? fmaxf(Er * bfLO(fc1[2]), E5r * bfHI(fc1[2])) : 0.f;
      float p7 = (ad1[3] != 0) ? fmaxf(Er * bfLO(fc1[3]), E5r * bfHI(fc1[3])) : 0.f;
      s_part += ((p0 + p1) + (p2 + p3)) + ((p4 + p5) + (p6 + p7));
      u32x4 pk;
      pk[0] = cvtpk(p0, p1); pk[1] = cvtpk(p2, p3);
      pk[2] = cvtpk(p4, p5); pk[3] = cvtpk(p6, p7);
      *(u32x4*)(ldsP + pw_byte) = pk;
    }

    // 3. pf(it+1) into the now-dead registers (wrap at tail: harmless dead load)
    ad0 = *(const i32x4*)(adjR + jn);
    ad1 = *(const i32x4*)(adjR + jn + 4);
    fc0 = *(const u32x4*)(fgR + jn);
    fc1 = *(const u32x4*)(fgR + jn + 4);

    // 4. P write visible to all waves
    asm volatile("s_waitcnt lgkmcnt(0)" ::: "memory");
    __builtin_amdgcn_s_barrier();

    // 5. consume: 4 k-steps x (1 A ds_read + 2 MFMA); B from regs (auto-waited)
    {
      s16x8 av0 = *(const s16x8*)(ldsP + ra * 128 + ((0 * 32 + khb) ^ swzA));
      s16x8 av1 = *(const s16x8*)(ldsP + ra * 128 + ((1 * 32 + khb) ^ swzA));
      s16x8 av2 = *(const s16x8*)(ldsP + ra * 128 + ((2 * 32 + khb) ^ swzA));
      s16x8 av3 = *(const s16x8*)(ldsP + ra * 128 + ((3 * 32 + khb) ^ swzA));
      __builtin_amdgcn_s_setprio(1);
      acc0 = mfma32(av0, b00, acc0);
      acc1 = mfma32(av0, b01, acc1);
      acc0 = mfma32(av1, b10, acc0);
      acc1 = mfma32(av1, b11, acc1);
      acc0 = mfma32(av2, b20, acc0);
      acc1 = mfma32(av2, b21, acc1);
      acc0 = mfma32(av3, b30, acc0);
      acc1 = mfma32(av3, b31, acc1);
      __builtin_amdgcn_s_setprio(0);
    }

    // 6. A reads drained before next iter's P write
    asm volatile("s_waitcnt lgkmcnt(0)" ::: "memory");
    __builtin_amdgcn_s_barrier();
  }

  // ---- epilogue: partial rowsum (8 threads/row), bf16 partial acc ----
  float s = s_part;
#pragma unroll
  for (int m = 1; m <= 4; m <<= 1) s += __shfl_xor(s, m, 64);
  if ((tid & 7) == 0) ps[(size_t)ks * N + r0 + r] = s;

  unsigned short* po = pacc + (size_t)ks * N * F;
#pragma unroll
  for (int g = 0; g < 16; ++g) {
    int orow = rg * 32 + (g & 3) + 8 * (g >> 2) + 4 * (l >> 5);
    unsigned short* pr = po + (size_t)(r0 + orow) * F + colb;
    pr[0]  = (unsigned short)f2bf(acc0[g]);
    pr[32] = (unsigned short)f2bf(acc1[g]);
  }
}

// ---------------- combine 4 bf16 split-K partials, normalize, ELU ---------------
__global__ __launch_bounds__(256) void k_combine(const unsigned short* __restrict__ pacc,
                                                 const float* __restrict__ ps,
                                                 float* __restrict__ out) {
  int t = blockIdx.x * 256 + threadIdx.x;  // 524288 threads, 4 feats each
  size_t idx = (size_t)t * 4;
  int row = (int)(idx >> 8);
  f32x4 sum;
#pragma unroll
  for (int i = 0; i < 4; ++i) sum[i] = 0.f;
#pragma unroll
  for (int k = 0; k < 4; ++k) {
    u32x2 q = *(const u32x2*)(pacc + (size_t)k * N * F + idx);
    sum[0] += bfLO(q[0]); sum[1] += bfHI(q[0]);
    sum[2] += bfLO(q[1]); sum[3] += bfHI(q[1]);
  }
  float inv = 1.f / (ps[row] + ps[N + row] + ps[2 * N + row] + ps[3 * N + row]);
  f32x4 o;
#pragma unroll
  for (int i = 0; i < 4; ++i) {
    float v = sum[i] * inv;
    o[i] = v > 0.f ? v : expm1f(v);
  }
  *(f32x4*)(out + idx) = o;
}

extern "C" void kernel_launch(void* const* d_in, const int* in_sizes, int n_in,
                              void* d_out, int out_size, void* d_ws, size_t ws_size,
                              hipStream_t stream) {
  const float* input = (const float*)d_in[0];
  const int*   adj   = (const int*)d_in[1];
  const float* W     = (const float*)d_in[2];
  const float* a     = (const float*)d_in[3];
  float* out = (float*)d_out;
  char* ws = (char*)d_ws;

  // pacc (16 MB, bf16) aliases Wt (dead before k_phase2 runs).
  unsigned short* pacc = (unsigned short*)(ws);              // 16,777,216 B @0
  unsigned short* Wt   = (unsigned short*)(ws + 8388608);    //    262,144 B
  unsigned short* Hj   = (unsigned short*)(ws + 16777216);   //  4,194,304 B
  float*    E  = (float*)(ws + 20971520);                    //     32,768 B
  float*    E5 = (float*)(ws + 21004288);                    //     32,768 B
  unsigned* FG = (unsigned*)(ws + 21037056);                 //     32,768 B
  float*    ps = (float*)(ws + 21069824);                    //    131,072 B -> 21.2 MB

  hipLaunchKernelGGL(k_prep_w, dim3(64),   dim3(256), 0, stream, W, Wt);
  hipLaunchKernelGGL(k_gemm1,  dim3(256),  dim3(512), 0, stream, input, Wt, a, Hj, E, E5, FG);
  hipLaunchKernelGGL(k_phase2, dim3(512),  dim3(512), 0, stream, adj, Hj, E, E5, FG, pacc, ps);
  hipLaunchKernelGGL(k_combine,dim3(2048), dim3(256), 0, stream, pacc, ps, out);
}